// Round 19
// baseline (219.468 us; speedup 1.0000x reference)
//
#include <hip/hip_runtime.h>
#include <hip/hip_bf16.h>

static constexpr int N = 100000;
static constexpr int HID = 128;
static constexpr int NBKT = (N + 127) / 128;  // 782 dst-buckets of 128 nodes
static constexpr int BCAP = 2560;             // per-bucket capacity (mean 2046, +11 sigma)
static constexpr int BEPB = 4096;             // edges per k_bucket block

typedef short v8s __attribute__((ext_vector_type(8)));
typedef float v4f __attribute__((ext_vector_type(4)));
typedef unsigned short u16x8 __attribute__((ext_vector_type(8)));

// ---------- bf16 helpers (RNE) ----------
static __device__ __forceinline__ unsigned short f2bf(float x) {
  unsigned u = __float_as_uint(x);
  return (unsigned short)((u + 0x7fffu + ((u >> 16) & 1u)) >> 16);
}
static __device__ __forceinline__ float bf2f(unsigned short u) {
  return __uint_as_float(((unsigned)u) << 16);
}

// ---------- One-time weight prep (split-bf16, MFMA-fragment-ordered) + bcur init ----------
__global__ void k_wprep(const float* __restrict__ ws2, const float* __restrict__ wn2,
                        unsigned short* __restrict__ wp, unsigned* __restrict__ bcur) {
  int id = blockIdx.x * 64 + threadIdx.x;
  if (id < NBKT) bcur[id] = (unsigned)id * BCAP;
  int b = blockIdx.x;     // mat(2) x ks(4) x cf(8)
  int mat = b >> 5;
  int ks = (b >> 3) & 3;
  int cf = b & 7;
  int l = threadIdx.x;
  const float* W = mat ? wn2 : ws2;
  int col = cf * 16 + (l & 15);
  int k0 = ks * 32 + (l >> 4) * 8;
  u16x8 h8, l8;
#pragma unroll
  for (int i = 0; i < 8; ++i) {
    float w = W[(k0 + i) * 128 + col];
    unsigned short h = f2bf(w);
    h8[i] = h;
    l8[i] = f2bf(w - bf2f(h));
  }
  int fhi = (ks * 4 + mat) * 8 + cf;
  int flo = (ks * 4 + mat + 2) * 8 + cf;
  *reinterpret_cast<u16x8*>(wp + fhi * 512 + l * 8) = h8;
  *reinterpret_cast<u16x8*>(wp + flo * 512 + l * 8) = l8;
}

// ---------- Bucket edges by dst>>7: LDS hist + per-(block,bucket) reservation (R16) ----------
__global__ __launch_bounds__(256) void k_bucket(const int* __restrict__ src,
                                                const int* __restrict__ dst,
                                                unsigned* __restrict__ bcur,
                                                unsigned* __restrict__ bucket, int E) {
  __shared__ unsigned hist[NBKT];
  __shared__ unsigned base[NBKT];
  for (int i = threadIdx.x; i < NBKT; i += 256) hist[i] = 0;
  __syncthreads();
  const int e0 = blockIdx.x * BEPB;
  const int n = min(e0 + BEPB, E) - e0;

  unsigned pk[16];
  int bk[16];
#pragma unroll
  for (int i = 0; i < 16; ++i) {
    int e = threadIdx.x + 256 * i;
    if (e < n) {
      int d = __builtin_nontemporal_load(dst + e0 + e);
      int s = __builtin_nontemporal_load(src + e0 + e);
      int b = d >> 7;
      pk[i] = ((unsigned)s << 7) | (unsigned)(d & 127);
      bk[i] = b;
      atomicAdd(&hist[b], 1u);
    } else {
      bk[i] = -1;
      pk[i] = 0;
    }
  }
  __syncthreads();
  for (int i = threadIdx.x; i < NBKT; i += 256) {
    unsigned h = hist[i];
    base[i] = h ? atomicAdd(&bcur[i], h) : 0u;
    hist[i] = 0;  // reuse as local cursor
  }
  __syncthreads();
#pragma unroll
  for (int i = 0; i < 16; ++i) {
    if (bk[i] >= 0) {
      unsigned pos = base[bk[i]] + atomicAdd(&hist[bk[i]], 1u);
      bucket[pos] = pk[i];
    }
  }
}

// ---------- Exclusive scan over bucket counts -> csr-space bucket bases ----------
__global__ void k_bucketscan(const unsigned* __restrict__ bcur, unsigned* __restrict__ bbase) {
  __shared__ unsigned s[1024];
  int t = threadIdx.x;
  unsigned v = (t < NBKT) ? (bcur[t] - (unsigned)t * BCAP) : 0u;
  s[t] = v;
  __syncthreads();
  for (int off = 1; off < 1024; off <<= 1) {
    unsigned x = (t >= off) ? s[t - off] : 0u;
    __syncthreads();
    s[t] += x;
    __syncthreads();
  }
  if (t < NBKT) bbase[t] = s[t] - v;  // exclusive
}

// ---------- Per-bucket CSR + FUSED layer-1 ----------
// Phase A: bucket read + LDS hist + LDS f32 feats-sum (the layer-1 gather, done once).
// Then scan -> roff/cnt/csr as before; dense 4->128 + relu -> h1 (no separate k_layer1).
__global__ __launch_bounds__(256) void k_csr(
    const unsigned* __restrict__ bcur, const unsigned* __restrict__ bbase,
    const unsigned* __restrict__ bucket, const float* __restrict__ feats,
    const float* __restrict__ ws1, const float* __restrict__ wn1,
    const float* __restrict__ b1, unsigned* __restrict__ cnt,
    unsigned* __restrict__ roff, int* __restrict__ csr,
    unsigned short* __restrict__ h1) {
  const int b = blockIdx.x;
  const unsigned segbase = (unsigned)b * BCAP;
  const unsigned n = bcur[b] - segbase;  // edges in this bucket
  const int v0 = b << 7;
  __shared__ unsigned h[128];
  __shared__ unsigned rowoff[128];
  __shared__ unsigned s[128];
  __shared__ unsigned ccnt[128];
  __shared__ float macc[128][4];  // per-node 4-dim feats sum
  const int t = threadIdx.x;
  if (t < 128) {
    h[t] = 0;
    macc[t][0] = 0.f; macc[t][1] = 0.f; macc[t][2] = 0.f; macc[t][3] = 0.f;
  }
  __syncthreads();

  // Phase A: hoisted bucket loads, then feats gather + LDS accumulation.
  unsigned pk[10];  // BCAP/256 = 10
#pragma unroll
  for (int i = 0; i < 10; ++i) {
    unsigned idx = t + 256u * i;
    pk[i] = (idx < n) ? bucket[segbase + idx] : 0xffffffffu;
  }
#pragma unroll
  for (int i = 0; i < 10; ++i) {
    if (pk[i] != 0xffffffffu) {
      unsigned dl = pk[i] & 127u;
      int sv = (int)(pk[i] >> 7);
      float4 f = *reinterpret_cast<const float4*>(feats + 4 * sv);
      atomicAdd(&h[dl], 1u);
      atomicAdd(&macc[dl][0], f.x);
      atomicAdd(&macc[dl][1], f.y);
      atomicAdd(&macc[dl][2], f.z);
      atomicAdd(&macc[dl][3], f.w);
    }
  }
  __syncthreads();

  // Exclusive scan of h[0..127] -> row starts.
  unsigned val = (t < 128) ? h[t] : 0u;
  if (t < 128) s[t] = val;
  __syncthreads();
  for (int off = 1; off < 128; off <<= 1) {
    unsigned x = (t < 128 && t >= off) ? s[t - off] : 0u;
    __syncthreads();
    if (t < 128) s[t] += x;
    __syncthreads();
  }
  if (t < 128) {
    int v = v0 + t;
    if (v < N) {
      unsigned rstart = bbase[b] + s[t] - val;
      rowoff[t] = rstart;
      roff[v] = rstart;
      cnt[v] = val;
    }
    ccnt[t] = val;
    h[t] = 0;  // reuse as row cursor
  }
  __syncthreads();

  // CSR scatter (L2-local window).
#pragma unroll
  for (int i = 0; i < 10; ++i) {
    if (pk[i] != 0xffffffffu) {
      unsigned dl = pk[i] & 127u;
      unsigned pos = rowoff[dl] + atomicAdd(&h[dl], 1u);
      csr[pos] = (int)(pk[i] >> 7);
    }
  }

  // Dense layer-1: 2 threads per node, 64 cols each. h1 = relu(b1 + fv@ws1 + mean4@wn1).
  const int vl = t >> 1;
  const int ch = (t & 1) * 64;
  const int v = v0 + vl;
  if (v < N) {
    float inv = 1.0f / fmaxf((float)ccnt[vl], 1.0f);
    float m0 = macc[vl][0] * inv, m1 = macc[vl][1] * inv;
    float m2 = macc[vl][2] * inv, m3 = macc[vl][3] * inv;
    float4 fv = *reinterpret_cast<const float4*>(feats + 4 * v);
#pragma unroll
    for (int g = 0; g < 8; ++g) {
      const int c0 = ch + 8 * g;
      unsigned o[4];
#pragma unroll
      for (int half = 0; half < 2; ++half) {
        float4 bv = *reinterpret_cast<const float4*>(b1 + c0 + 4 * half);
        float ob[4] = {bv.x, bv.y, bv.z, bv.w};
#pragma unroll
        for (int k = 0; k < 4; ++k) {
          float4 wsv = *reinterpret_cast<const float4*>(ws1 + k * 128 + c0 + 4 * half);
          float4 wnv = *reinterpret_cast<const float4*>(wn1 + k * 128 + c0 + 4 * half);
          float fk = (k == 0) ? fv.x : (k == 1) ? fv.y : (k == 2) ? fv.z : fv.w;
          float mk = (k == 0) ? m0 : (k == 1) ? m1 : (k == 2) ? m2 : m3;
          ob[0] += fk * wsv.x + mk * wnv.x;
          ob[1] += fk * wsv.y + mk * wnv.y;
          ob[2] += fk * wsv.z + mk * wnv.z;
          ob[3] += fk * wsv.w + mk * wnv.w;
        }
#pragma unroll
        for (int jj = 0; jj < 2; ++jj) {
          float lo = fmaxf(ob[2 * jj], 0.f), hi = fmaxf(ob[2 * jj + 1], 0.f);
          o[2 * half + jj] = (unsigned)f2bf(lo) | (((unsigned)f2bf(hi)) << 16);
        }
      }
      *reinterpret_cast<uint4*>(h1 + (size_t)v * HID + c0) =
          make_uint4(o[0], o[1], o[2], o[3]);
    }
  }
}

// ---------- 128-dim mean aggregation: TWO nodes per wave, 4-deep, unpredicated (R13) ----------
__global__ void k_agg(const unsigned* __restrict__ cnt, const unsigned* __restrict__ roff,
                      const int* __restrict__ csr, const unsigned short* __restrict__ h1,
                      unsigned short* __restrict__ mean) {
  const int wv = threadIdx.x >> 6;
  const int lane = threadIdx.x & 63;
  const int hl = lane & 31;               // lane within half-wave
  const int v = blockIdx.x * 8 + wv * 2 + (lane >> 5);
  if (v >= N) return;
  const unsigned c = cnt[v];
  const unsigned start = roff[v];
  const unsigned short* __restrict__ hrow = h1 + hl * 4;

  float a0 = 0.f, a1 = 0.f, a2 = 0.f, a3 = 0.f;
  float b0 = 0.f, b1 = 0.f, b2 = 0.f, b3 = 0.f;

  const unsigned cm = c & ~3u;
  unsigned e = 0;
  for (; e < cm; e += 4) {
    int s[4];
#pragma unroll
    for (int q = 0; q < 4; ++q) s[q] = csr[start + e + q];
    uint2 pk[4];
#pragma unroll
    for (int q = 0; q < 4; ++q)
      pk[q] = *reinterpret_cast<const uint2*>(hrow + (size_t)s[q] * HID);
#pragma unroll
    for (int q = 0; q < 4; ++q) {
      float f0 = __uint_as_float(pk[q].x << 16);
      float f1 = __uint_as_float(pk[q].x & 0xffff0000u);
      float f2 = __uint_as_float(pk[q].y << 16);
      float f3 = __uint_as_float(pk[q].y & 0xffff0000u);
      if (q & 1) { b0 += f0; b1 += f1; b2 += f2; b3 += f3; }
      else       { a0 += f0; a1 += f1; a2 += f2; a3 += f3; }
    }
  }
  for (; e < c; ++e) {
    int s = csr[start + e];
    uint2 pk = *reinterpret_cast<const uint2*>(hrow + (size_t)s * HID);
    a0 += __uint_as_float(pk.x << 16);
    a1 += __uint_as_float(pk.x & 0xffff0000u);
    a2 += __uint_as_float(pk.y << 16);
    a3 += __uint_as_float(pk.y & 0xffff0000u);
  }
  float inv = 1.0f / fmaxf((float)c, 1.0f);
  a0 = (a0 + b0) * inv; a1 = (a1 + b1) * inv;
  a2 = (a2 + b2) * inv; a3 = (a3 + b3) * inv;
  uint2 o;
  o.x = (unsigned)f2bf(a0) | (((unsigned)f2bf(a1)) << 16);
  o.y = (unsigned)f2bf(a2) | (((unsigned)f2bf(a3)) << 16);
  *reinterpret_cast<uint2*>(mean + (size_t)v * HID + hl * 4) = o;
}

// ---------- Layer 2 + head: 16 rows per WAVE, A hoisted (R16 best-measured) ----------
__global__ __launch_bounds__(256) void k_l2_mfma(
    const unsigned short* __restrict__ h1, const unsigned short* __restrict__ mean,
    const unsigned short* __restrict__ wp, const float* __restrict__ b2,
    const float* __restrict__ wout, const float* __restrict__ bout,
    float* __restrict__ out) {
  const int l = threadIdx.x & 63;
  const int wv = threadIdx.x >> 6;
  const size_t vbase = (size_t)blockIdx.x * 64 + (size_t)wv * 16;  // 16 rows per wave
  const int rlane = l & 15;
  const int kg = l >> 4;

  // Hoist ALL A-fragment loads (8 independent dwordx4) before any MFMA.
  size_t hr = vbase + rlane;
  if (hr >= N) hr = N - 1;  // tail clamp (store guarded)
  v8s ah[4], am[4];
#pragma unroll
  for (int ks = 0; ks < 4; ++ks) {
    size_t off = hr * HID + ks * 32 + kg * 8;
    ah[ks] = *reinterpret_cast<const v8s*>(h1 + off);
    am[ks] = *reinterpret_cast<const v8s*>(mean + off);
  }

  v4f acc[8];
#pragma unroll
  for (int cf = 0; cf < 8; ++cf) acc[cf] = (v4f)(0.f);

#pragma unroll
  for (int ks = 0; ks < 4; ++ks) {
#pragma unroll
    for (int m = 0; m < 4; ++m) {  // Ws_hi, Wn_hi, Ws_lo, Wn_lo
#pragma unroll
      for (int cf = 0; cf < 8; ++cf) {
        v8s bf = *reinterpret_cast<const v8s*>(wp + ((ks * 4 + m) * 8 + cf) * 512 + l * 8);
        acc[cf] = __builtin_amdgcn_mfma_f32_16x16x32_bf16(
            (m & 1) ? am[ks] : ah[ks], bf, acc[cf], 0, 0, 0);
      }
    }
  }

  // Epilogue: h2 = relu(acc + b2), head out = h2 @ wout + bout.
  float b2c[8], w0c[8], w1c[8];
#pragma unroll
  for (int cf = 0; cf < 8; ++cf) {
    int col = cf * 16 + rlane;
    b2c[cf] = b2[col];
    w0c[cf] = wout[col * 2 + 0];
    w1c[cf] = wout[col * 2 + 1];
  }
  const float bo0 = bout[0], bo1 = bout[1];
#pragma unroll
  for (int j = 0; j < 4; ++j) {
    float s0 = 0.f, s1 = 0.f;
#pragma unroll
    for (int cf = 0; cf < 8; ++cf) {
      float h2 = fmaxf(acc[cf][j] + b2c[cf], 0.f);
      s0 += h2 * w0c[cf];
      s1 += h2 * w1c[cf];
    }
#pragma unroll
    for (int off = 1; off < 16; off <<= 1) {
      s0 += __shfl_xor(s0, off);
      s1 += __shfl_xor(s1, off);
    }
    size_t row = vbase + kg * 4 + j;
    if (row < N) {
      if (rlane == 0) out[row * 2 + 0] = s0 + bo0;
      if (rlane == 1) out[row * 2 + 1] = s1 + bo1;
    }
  }
}

extern "C" void kernel_launch(void* const* d_in, const int* in_sizes, int n_in,
                              void* d_out, int out_size, void* d_ws, size_t ws_size,
                              hipStream_t stream) {
  const float* feats = (const float*)d_in[0];
  const int* src = (const int*)d_in[1];
  const int* dst = (const int*)d_in[2];
  const float* ws1 = (const float*)d_in[3];
  const float* wn1 = (const float*)d_in[4];
  const float* b1 = (const float*)d_in[5];
  const float* ws2 = (const float*)d_in[6];
  const float* wn2 = (const float*)d_in[7];
  const float* b2 = (const float*)d_in[8];
  const float* wout = (const float*)d_in[9];
  const float* bout = (const float*)d_in[10];
  float* out = (float*)d_out;
  const int E = in_sizes[1];

  // Workspace layout (16B-aligned):
  char* p = (char*)d_ws;
  unsigned* bcur = (unsigned*)p;             p += 784 * 4;
  unsigned* bbase = (unsigned*)p;            p += 784 * 4;
  unsigned* bucket = (unsigned*)p;           p += (size_t)NBKT * BCAP * 4;  // 8MB
  int* csr = (int*)p;                        p += (size_t)E * 4;
  unsigned* cnt = (unsigned*)p;              p += (size_t)N * 4;
  unsigned* roff = (unsigned*)p;             p += (size_t)N * 4;
  unsigned short* h1 = (unsigned short*)p;   p += (size_t)N * HID * 2;
  unsigned short* mean = (unsigned short*)p; p += (size_t)N * HID * 2;
  unsigned short* wp = (unsigned short*)p;   // 4*128*128 bf16 = 128KB

  int bgrid = (E + BEPB - 1) / BEPB;
  k_wprep<<<64, 64, 0, stream>>>(ws2, wn2, wp, bcur);
  k_bucket<<<bgrid, 256, 0, stream>>>(src, dst, bcur, bucket, E);
  k_bucketscan<<<1, 1024, 0, stream>>>(bcur, bbase);
  k_csr<<<NBKT, 256, 0, stream>>>(bcur, bbase, bucket, feats, ws1, wn1, b1,
                                  cnt, roff, csr, h1);
  k_agg<<<(N + 7) / 8, 256, 0, stream>>>(cnt, roff, csr, h1, mean);
  k_l2_mfma<<<(N + 63) / 64, 256, 0, stream>>>(h1, mean, wp, b2, wout, bout, out);
}

// Round 20
// 168.563 us; speedup vs baseline: 1.3020x; 1.3020x over previous
//
#include <hip/hip_runtime.h>
#include <hip/hip_bf16.h>

static constexpr int N = 100000;
static constexpr int HID = 128;
static constexpr int NBKT = (N + 127) / 128;  // 782 dst-buckets of 128 nodes
static constexpr int BCAP = 2560;             // per-bucket capacity (mean 2046, +11 sigma)
static constexpr int BEPB = 4096;             // edges per k_bucket block

typedef short v8s __attribute__((ext_vector_type(8)));
typedef float v4f __attribute__((ext_vector_type(4)));
typedef unsigned short u16x8 __attribute__((ext_vector_type(8)));

// ---------- bf16 helpers (RNE) ----------
static __device__ __forceinline__ unsigned short f2bf(float x) {
  unsigned u = __float_as_uint(x);
  return (unsigned short)((u + 0x7fffu + ((u >> 16) & 1u)) >> 16);
}
static __device__ __forceinline__ float bf2f(unsigned short u) {
  return __uint_as_float(((unsigned)u) << 16);
}

// ---------- One-time weight prep (split-bf16, MFMA-fragment-ordered) + bcur init ----------
__global__ void k_wprep(const float* __restrict__ ws2, const float* __restrict__ wn2,
                        unsigned short* __restrict__ wp, unsigned* __restrict__ bcur) {
  int id = blockIdx.x * 64 + threadIdx.x;
  if (id < NBKT) bcur[id] = (unsigned)id * BCAP;
  int b = blockIdx.x;     // mat(2) x ks(4) x cf(8)
  int mat = b >> 5;
  int ks = (b >> 3) & 3;
  int cf = b & 7;
  int l = threadIdx.x;
  const float* W = mat ? wn2 : ws2;
  int col = cf * 16 + (l & 15);
  int k0 = ks * 32 + (l >> 4) * 8;
  u16x8 h8, l8;
#pragma unroll
  for (int i = 0; i < 8; ++i) {
    float w = W[(k0 + i) * 128 + col];
    unsigned short h = f2bf(w);
    h8[i] = h;
    l8[i] = f2bf(w - bf2f(h));
  }
  int fhi = (ks * 4 + mat) * 8 + cf;
  int flo = (ks * 4 + mat + 2) * 8 + cf;
  *reinterpret_cast<u16x8*>(wp + fhi * 512 + l * 8) = h8;
  *reinterpret_cast<u16x8*>(wp + flo * 512 + l * 8) = l8;
}

// ---------- Bucket edges by dst>>7: LDS hist + per-(block,bucket) reservation ----------
__global__ __launch_bounds__(256) void k_bucket(const int* __restrict__ src,
                                                const int* __restrict__ dst,
                                                unsigned* __restrict__ bcur,
                                                unsigned* __restrict__ bucket, int E) {
  __shared__ unsigned hist[NBKT];
  __shared__ unsigned base[NBKT];
  for (int i = threadIdx.x; i < NBKT; i += 256) hist[i] = 0;
  __syncthreads();
  const int e0 = blockIdx.x * BEPB;
  const int n = min(e0 + BEPB, E) - e0;

  unsigned pk[16];
  int bk[16];
#pragma unroll
  for (int i = 0; i < 16; ++i) {
    int e = threadIdx.x + 256 * i;
    if (e < n) {
      int d = __builtin_nontemporal_load(dst + e0 + e);
      int s = __builtin_nontemporal_load(src + e0 + e);
      int b = d >> 7;
      pk[i] = ((unsigned)s << 7) | (unsigned)(d & 127);
      bk[i] = b;
      atomicAdd(&hist[b], 1u);
    } else {
      bk[i] = -1;
      pk[i] = 0;
    }
  }
  __syncthreads();
  for (int i = threadIdx.x; i < NBKT; i += 256) {
    unsigned h = hist[i];
    base[i] = h ? atomicAdd(&bcur[i], h) : 0u;
    hist[i] = 0;  // reuse as local cursor
  }
  __syncthreads();
#pragma unroll
  for (int i = 0; i < 16; ++i) {
    if (bk[i] >= 0) {
      unsigned pos = base[bk[i]] + atomicAdd(&hist[bk[i]], 1u);
      bucket[pos] = pk[i];
    }
  }
}

// ---------- Exclusive scan over bucket counts -> csr-space bucket bases ----------
__global__ void k_bucketscan(const unsigned* __restrict__ bcur, unsigned* __restrict__ bbase) {
  __shared__ unsigned s[1024];
  int t = threadIdx.x;
  unsigned v = (t < NBKT) ? (bcur[t] - (unsigned)t * BCAP) : 0u;
  s[t] = v;
  __syncthreads();
  for (int off = 1; off < 1024; off <<= 1) {
    unsigned x = (t >= off) ? s[t - off] : 0u;
    __syncthreads();
    s[t] += x;
    __syncthreads();
  }
  if (t < NBKT) bbase[t] = s[t] - v;  // exclusive
}

// ---------- Per-bucket CSR: hist 128 nodes, scan, write cnt/roff, scatter csr ----------
__global__ __launch_bounds__(256) void k_csr(const unsigned* __restrict__ bcur,
                                             const unsigned* __restrict__ bbase,
                                             const unsigned* __restrict__ bucket,
                                             unsigned* __restrict__ cnt,
                                             unsigned* __restrict__ roff,
                                             int* __restrict__ csr) {
  const int b = blockIdx.x;
  const unsigned segbase = (unsigned)b * BCAP;
  const unsigned n = bcur[b] - segbase;  // edges in this bucket
  const int v0 = b << 7;
  __shared__ unsigned h[128];
  __shared__ unsigned rowoff[128];
  __shared__ unsigned s[128];
  if (threadIdx.x < 128) h[threadIdx.x] = 0;
  __syncthreads();

  unsigned pk[10];  // BCAP/256 = 10
#pragma unroll
  for (int i = 0; i < 10; ++i) {
    unsigned idx = threadIdx.x + 256u * i;
    if (idx < n) {
      pk[i] = bucket[segbase + idx];
      atomicAdd(&h[pk[i] & 127u], 1u);
    } else {
      pk[i] = 0xffffffffu;
    }
  }
  __syncthreads();

  unsigned val = (threadIdx.x < 128) ? h[threadIdx.x] : 0u;
  if (threadIdx.x < 128) s[threadIdx.x] = val;
  __syncthreads();
  for (int off = 1; off < 128; off <<= 1) {
    unsigned x = (threadIdx.x < 128 && threadIdx.x >= off) ? s[threadIdx.x - off] : 0u;
    __syncthreads();
    if (threadIdx.x < 128) s[threadIdx.x] += x;
    __syncthreads();
  }
  if (threadIdx.x < 128) {
    int v = v0 + threadIdx.x;
    if (v < N) {
      unsigned rstart = bbase[b] + s[threadIdx.x] - val;
      rowoff[threadIdx.x] = rstart;
      roff[v] = rstart;
      cnt[v] = val;
    }
    h[threadIdx.x] = 0;  // reuse as row cursor
  }
  __syncthreads();

#pragma unroll
  for (int i = 0; i < 10; ++i) {
    if (pk[i] != 0xffffffffu) {
      unsigned dl = pk[i] & 127u;
      unsigned pos = rowoff[dl] + atomicAdd(&h[dl], 1u);
      csr[pos] = (int)(pk[i] >> 7);
    }
  }
}

// ---------- Layer 1: one QUARTER-WAVE (16 lanes) per node ----------
__global__ void k_layer1(const float* __restrict__ feats, const unsigned* __restrict__ cnt,
                         const unsigned* __restrict__ roff, const int* __restrict__ csr,
                         const float* __restrict__ ws1, const float* __restrict__ wn1,
                         const float* __restrict__ b1, unsigned short* __restrict__ h1) {
  const int v = blockIdx.x * 16 + (threadIdx.x >> 4);
  const int l = threadIdx.x & 15;
  if (v >= N) return;
  const unsigned c = cnt[v];
  const unsigned start = roff[v];
  float4 acc = make_float4(0.f, 0.f, 0.f, 0.f);
  for (unsigned e = l; e < c; e += 16) {
    int s = csr[start + e];
    float4 f = *reinterpret_cast<const float4*>(feats + 4 * s);
    acc.x += f.x; acc.y += f.y; acc.z += f.z; acc.w += f.w;
  }
#pragma unroll
  for (int off = 1; off < 16; off <<= 1) {
    acc.x += __shfl_xor(acc.x, off);
    acc.y += __shfl_xor(acc.y, off);
    acc.z += __shfl_xor(acc.z, off);
    acc.w += __shfl_xor(acc.w, off);
  }
  float inv = 1.0f / fmaxf((float)c, 1.0f);
  float m0 = acc.x * inv, m1 = acc.y * inv, m2 = acc.z * inv, m3 = acc.w * inv;
  float4 fv = *reinterpret_cast<const float4*>(feats + 4 * v);
  const int c0 = l * 8;
  unsigned o[4];
#pragma unroll
  for (int half = 0; half < 2; ++half) {
    float4 bv = *reinterpret_cast<const float4*>(b1 + c0 + 4 * half);
    float ob[4] = {bv.x, bv.y, bv.z, bv.w};
#pragma unroll
    for (int k = 0; k < 4; ++k) {
      float4 wsv = *reinterpret_cast<const float4*>(ws1 + k * 128 + c0 + 4 * half);
      float4 wnv = *reinterpret_cast<const float4*>(wn1 + k * 128 + c0 + 4 * half);
      float fk = (k == 0) ? fv.x : (k == 1) ? fv.y : (k == 2) ? fv.z : fv.w;
      float mk = (k == 0) ? m0 : (k == 1) ? m1 : (k == 2) ? m2 : m3;
      ob[0] += fk * wsv.x + mk * wnv.x;
      ob[1] += fk * wsv.y + mk * wnv.y;
      ob[2] += fk * wsv.z + mk * wnv.z;
      ob[3] += fk * wsv.w + mk * wnv.w;
    }
#pragma unroll
    for (int jj = 0; jj < 2; ++jj) {
      float lo = fmaxf(ob[2 * jj], 0.f), hi = fmaxf(ob[2 * jj + 1], 0.f);
      o[2 * half + jj] = (unsigned)f2bf(lo) | (((unsigned)f2bf(hi)) << 16);
    }
  }
  *reinterpret_cast<uint4*>(h1 + (size_t)v * HID + c0) =
      make_uint4(o[0], o[1], o[2], o[3]);
}

// ---------- 128-dim mean aggregation: TWO nodes per wave, 4-deep, unpredicated (R13) ----------
__global__ void k_agg(const unsigned* __restrict__ cnt, const unsigned* __restrict__ roff,
                      const int* __restrict__ csr, const unsigned short* __restrict__ h1,
                      unsigned short* __restrict__ mean) {
  const int wv = threadIdx.x >> 6;
  const int lane = threadIdx.x & 63;
  const int hl = lane & 31;               // lane within half-wave
  const int v = blockIdx.x * 8 + wv * 2 + (lane >> 5);
  if (v >= N) return;
  const unsigned c = cnt[v];
  const unsigned start = roff[v];
  const unsigned short* __restrict__ hrow = h1 + hl * 4;

  float a0 = 0.f, a1 = 0.f, a2 = 0.f, a3 = 0.f;
  float b0 = 0.f, b1 = 0.f, b2 = 0.f, b3 = 0.f;

  const unsigned cm = c & ~3u;
  unsigned e = 0;
  for (; e < cm; e += 4) {
    int s[4];
#pragma unroll
    for (int q = 0; q < 4; ++q) s[q] = csr[start + e + q];
    uint2 pk[4];
#pragma unroll
    for (int q = 0; q < 4; ++q)
      pk[q] = *reinterpret_cast<const uint2*>(hrow + (size_t)s[q] * HID);
#pragma unroll
    for (int q = 0; q < 4; ++q) {
      float f0 = __uint_as_float(pk[q].x << 16);
      float f1 = __uint_as_float(pk[q].x & 0xffff0000u);
      float f2 = __uint_as_float(pk[q].y << 16);
      float f3 = __uint_as_float(pk[q].y & 0xffff0000u);
      if (q & 1) { b0 += f0; b1 += f1; b2 += f2; b3 += f3; }
      else       { a0 += f0; a1 += f1; a2 += f2; a3 += f3; }
    }
  }
  for (; e < c; ++e) {
    int s = csr[start + e];
    uint2 pk = *reinterpret_cast<const uint2*>(hrow + (size_t)s * HID);
    a0 += __uint_as_float(pk.x << 16);
    a1 += __uint_as_float(pk.x & 0xffff0000u);
    a2 += __uint_as_float(pk.y << 16);
    a3 += __uint_as_float(pk.y & 0xffff0000u);
  }
  float inv = 1.0f / fmaxf((float)c, 1.0f);
  a0 = (a0 + b0) * inv; a1 = (a1 + b1) * inv;
  a2 = (a2 + b2) * inv; a3 = (a3 + b3) * inv;
  uint2 o;
  o.x = (unsigned)f2bf(a0) | (((unsigned)f2bf(a1)) << 16);
  o.y = (unsigned)f2bf(a2) | (((unsigned)f2bf(a3)) << 16);
  *reinterpret_cast<uint2*>(mean + (size_t)v * HID + hl * 4) = o;
}

// ---------- Layer 2 + head: 16 rows per WAVE, all A-fragments loaded upfront ----------
__global__ __launch_bounds__(256) void k_l2_mfma(
    const unsigned short* __restrict__ h1, const unsigned short* __restrict__ mean,
    const unsigned short* __restrict__ wp, const float* __restrict__ b2,
    const float* __restrict__ wout, const float* __restrict__ bout,
    float* __restrict__ out) {
  const int l = threadIdx.x & 63;
  const int wv = threadIdx.x >> 6;
  const size_t vbase = (size_t)blockIdx.x * 64 + (size_t)wv * 16;  // 16 rows per wave
  const int rlane = l & 15;
  const int kg = l >> 4;

  // Hoist ALL A-fragment loads (8 independent dwordx4) before any MFMA.
  size_t hr = vbase + rlane;
  if (hr >= N) hr = N - 1;  // tail clamp (store guarded)
  v8s ah[4], am[4];
#pragma unroll
  for (int ks = 0; ks < 4; ++ks) {
    size_t off = hr * HID + ks * 32 + kg * 8;
    ah[ks] = *reinterpret_cast<const v8s*>(h1 + off);
    am[ks] = *reinterpret_cast<const v8s*>(mean + off);
  }

  v4f acc[8];
#pragma unroll
  for (int cf = 0; cf < 8; ++cf) acc[cf] = (v4f)(0.f);

#pragma unroll
  for (int ks = 0; ks < 4; ++ks) {
#pragma unroll
    for (int m = 0; m < 4; ++m) {  // Ws_hi, Wn_hi, Ws_lo, Wn_lo
#pragma unroll
      for (int cf = 0; cf < 8; ++cf) {
        v8s bf = *reinterpret_cast<const v8s*>(wp + ((ks * 4 + m) * 8 + cf) * 512 + l * 8);
        acc[cf] = __builtin_amdgcn_mfma_f32_16x16x32_bf16(
            (m & 1) ? am[ks] : ah[ks], bf, acc[cf], 0, 0, 0);
      }
    }
  }

  // Epilogue: h2 = relu(acc + b2), head out = h2 @ wout + bout.
  float b2c[8], w0c[8], w1c[8];
#pragma unroll
  for (int cf = 0; cf < 8; ++cf) {
    int col = cf * 16 + rlane;
    b2c[cf] = b2[col];
    w0c[cf] = wout[col * 2 + 0];
    w1c[cf] = wout[col * 2 + 1];
  }
  const float bo0 = bout[0], bo1 = bout[1];
#pragma unroll
  for (int j = 0; j < 4; ++j) {
    float s0 = 0.f, s1 = 0.f;
#pragma unroll
    for (int cf = 0; cf < 8; ++cf) {
      float h2 = fmaxf(acc[cf][j] + b2c[cf], 0.f);
      s0 += h2 * w0c[cf];
      s1 += h2 * w1c[cf];
    }
#pragma unroll
    for (int off = 1; off < 16; off <<= 1) {
      s0 += __shfl_xor(s0, off);
      s1 += __shfl_xor(s1, off);
    }
    size_t row = vbase + kg * 4 + j;
    if (row < N) {
      if (rlane == 0) out[row * 2 + 0] = s0 + bo0;
      if (rlane == 1) out[row * 2 + 1] = s1 + bo1;
    }
  }
}

extern "C" void kernel_launch(void* const* d_in, const int* in_sizes, int n_in,
                              void* d_out, int out_size, void* d_ws, size_t ws_size,
                              hipStream_t stream) {
  const float* feats = (const float*)d_in[0];
  const int* src = (const int*)d_in[1];
  const int* dst = (const int*)d_in[2];
  const float* ws1 = (const float*)d_in[3];
  const float* wn1 = (const float*)d_in[4];
  const float* b1 = (const float*)d_in[5];
  const float* ws2 = (const float*)d_in[6];
  const float* wn2 = (const float*)d_in[7];
  const float* b2 = (const float*)d_in[8];
  const float* wout = (const float*)d_in[9];
  const float* bout = (const float*)d_in[10];
  float* out = (float*)d_out;
  const int E = in_sizes[1];

  // Workspace layout (16B-aligned):
  char* p = (char*)d_ws;
  unsigned* bcur = (unsigned*)p;             p += 784 * 4;
  unsigned* bbase = (unsigned*)p;            p += 784 * 4;
  unsigned* bucket = (unsigned*)p;           p += (size_t)NBKT * BCAP * 4;  // 8MB
  int* csr = (int*)p;                        p += (size_t)E * 4;
  unsigned* cnt = (unsigned*)p;              p += (size_t)N * 4;
  unsigned* roff = (unsigned*)p;             p += (size_t)N * 4;
  unsigned short* h1 = (unsigned short*)p;   p += (size_t)N * HID * 2;
  unsigned short* mean = (unsigned short*)p; p += (size_t)N * HID * 2;
  unsigned short* wp = (unsigned short*)p;   // 4*128*128 bf16 = 128KB

  int bgrid = (E + BEPB - 1) / BEPB;
  k_wprep<<<64, 64, 0, stream>>>(ws2, wn2, wp, bcur);
  k_bucket<<<bgrid, 256, 0, stream>>>(src, dst, bcur, bucket, E);
  k_bucketscan<<<1, 1024, 0, stream>>>(bcur, bbase);
  k_csr<<<NBKT, 256, 0, stream>>>(bcur, bbase, bucket, cnt, roff, csr);
  k_layer1<<<(N + 15) / 16, 256, 0, stream>>>(feats, cnt, roff, csr, ws1, wn1, b1, h1);
  k_agg<<<(N + 7) / 8, 256, 0, stream>>>(cnt, roff, csr, h1, mean);
  k_l2_mfma<<<(N + 63) / 64, 256, 0, stream>>>(h1, mean, wp, b2, wout, bout, out);
}